// Round 5
// baseline (345.695 us; speedup 1.0000x reference)
//
#include <hip/hip_runtime.h>
#include <math.h>

#define Bm 2048
#define Hm 512
#define Em 300
#define Tm 50
#define KWm 812   // H + E
#define KWp 832   // padded to multiple of 32

typedef unsigned short u16;
typedef unsigned int u32;
typedef __attribute__((ext_vector_type(8))) short short8;
typedef __attribute__((ext_vector_type(8))) u16 ushort8v;
typedef __attribute__((ext_vector_type(4))) float f32x4;

__device__ __forceinline__ float sigmoidf_(float x) { return 1.f / (1.f + __expf(-x)); }

// fp32 -> bf16 bits, round-to-nearest-even
__device__ __forceinline__ u16 bfr(float x) {
    union { float f; u32 u; } c; c.f = x;
    u32 u = c.u;
    u += 0x7FFFu + ((u >> 16) & 1u);
    return (u16)(u >> 16);
}
__device__ __forceinline__ ushort8v cvt8(const float* __restrict__ p) {
    f32x4 v0 = *(const f32x4*)p;
    f32x4 v1 = *(const f32x4*)(p + 4);
    ushort8v r;
    r[0] = bfr(v0[0]); r[1] = bfr(v0[1]); r[2] = bfr(v0[2]); r[3] = bfr(v0[3]);
    r[4] = bfr(v1[0]); r[5] = bfr(v1[1]); r[6] = bfr(v1[2]); r[7] = bfr(v1[3]);
    return r;
}

// async global(bf16,16B) -> LDS, linear dest (wave-uniform base + lane*16)
__device__ __forceinline__ void gload16(const u16* g, u16* l) {
    __builtin_amdgcn_global_load_lds((const __attribute__((address_space(1))) void*)g,
                                     (__attribute__((address_space(3))) void*)l, 16, 0, 0);
}

// ---------------------------------------------------------------------------
// k_pack_phi: phi fp32 [T*B*512] -> bf16, grid-stride, 8 elems/thread/iter.
// ---------------------------------------------------------------------------
__global__ __launch_bounds__(256) void k_pack_phi(
        const float* __restrict__ phi, u16* __restrict__ phib) {
    const size_t nvec = (size_t)Tm * Bm * 512 / 8;
    for (size_t i = (size_t)blockIdx.x * 256 + threadIdx.x; i < nvec;
         i += (size_t)gridDim.x * 256)
        *(ushort8v*)&phib[i * 8] = cvt8(phi + i * 8);
}

// ---------------------------------------------------------------------------
// k_pack: small bf16 conversions/concats.
// job 0: Aq[2048][1024] = bf16([h_enc | h_summ])
// job 1: Wq[512][1024]  = bf16([lq_w | ls_w])
// job 2: Wg[2048][832]  = bf16(W_w) zero-padded
// job 3: Xb[2048][512..831] = bf16(x) zero-padded
// job 4: lkwb[512][512] = bf16(lk_w)
// ---------------------------------------------------------------------------
__global__ __launch_bounds__(256) void k_pack(
        const float* __restrict__ henc, const float* __restrict__ hsum,
        const float* __restrict__ lq, const float* __restrict__ ls,
        const float* __restrict__ Ww, const float* __restrict__ x,
        const float* __restrict__ lkw,
        u16* __restrict__ Aq, u16* __restrict__ Wq,
        u16* __restrict__ Wg, u16* __restrict__ Xb, u16* __restrict__ lkwb) {
    const int job = blockIdx.y;
    const int r = blockIdx.x;
    const int tid = threadIdx.x;
    if (job == 0) {
        for (int c = tid; c < 1024; c += 256) {
            float v = (c < 512) ? henc[(size_t)r * 512 + c] : hsum[(size_t)r * 512 + (c - 512)];
            Aq[(size_t)r * 1024 + c] = bfr(v);
        }
    } else if (job == 1) {
        if (r < 512)
            for (int c = tid; c < 1024; c += 256) {
                float v = (c < 512) ? lq[(size_t)r * 512 + c] : ls[(size_t)r * 512 + (c - 512)];
                Wq[(size_t)r * 1024 + c] = bfr(v);
            }
    } else if (job == 2) {
        for (int c = tid; c < KWp; c += 256)
            Wg[(size_t)r * KWp + c] = (c < KWm) ? bfr(Ww[(size_t)r * KWm + c]) : (u16)0;
    } else if (job == 3) {
        for (int c = 512 + tid; c < KWp; c += 256)
            Xb[(size_t)r * KWp + c] = (c < KWm) ? bfr(x[(size_t)r * Em + (c - 512)]) : (u16)0;
    } else {
        if (r < 512)
            for (int c = tid; c < 512; c += 256)
                lkwb[(size_t)r * 512 + c] = bfr(lkw[(size_t)r * 512 + c]);
    }
}

// ---------------------------------------------------------------------------
// k_qs_mfma: qs[b,h] = [h_enc|h_summ]·[lq|ls]^T + (lq_b+ls_b+lk_b)[h]
// ---------------------------------------------------------------------------
__global__ __launch_bounds__(256) void k_qs_mfma(
        const u16* __restrict__ Aq, const u16* __restrict__ Wq,
        const float* __restrict__ lqb, const float* __restrict__ lsb,
        const float* __restrict__ lkb, float* __restrict__ qs) {
    __shared__ u16 Asl[64 * 32];
    __shared__ u16 Bsl[64 * 32];
    const int m0 = blockIdx.x * 64, n0 = blockIdx.y * 64;
    const int tid = threadIdx.x, lane = tid & 63, wid = tid >> 6;
    const int wr = wid >> 1, wc = wid & 1;
    const int l15 = lane & 15, l4 = lane >> 4;
    const int srow = (wid << 4) + (lane >> 2);
    const int gchunk = (lane & 3) ^ ((srow >> 1) & 3);
    f32x4 acc[2][2];
    #pragma unroll
    for (int i = 0; i < 2; ++i)
        #pragma unroll
        for (int j = 0; j < 2; ++j) acc[i][j] = (f32x4){0.f, 0.f, 0.f, 0.f};

    for (int k0 = 0; k0 < 1024; k0 += 32) {
        __syncthreads();
        gload16(Aq + (size_t)(m0 + srow) * 1024 + k0 + gchunk * 8, &Asl[wid * 512]);
        gload16(Wq + (size_t)(n0 + srow) * 1024 + k0 + gchunk * 8, &Bsl[wid * 512]);
        __syncthreads();
        short8 af[2], bf[2];
        #pragma unroll
        for (int mf = 0; mf < 2; ++mf) {
            int r = wr * 32 + mf * 16 + l15;
            af[mf] = *(const short8*)&Asl[r * 32 + (l4 ^ ((r >> 1) & 3)) * 8];
        }
        #pragma unroll
        for (int nf = 0; nf < 2; ++nf) {
            int r = wc * 32 + nf * 16 + l15;
            bf[nf] = *(const short8*)&Bsl[r * 32 + (l4 ^ ((r >> 1) & 3)) * 8];
        }
        #pragma unroll
        for (int mf = 0; mf < 2; ++mf)
            #pragma unroll
            for (int nf = 0; nf < 2; ++nf)
                acc[mf][nf] = __builtin_amdgcn_mfma_f32_16x16x32_bf16(
                                  af[mf], bf[nf], acc[mf][nf], 0, 0, 0);
    }
    #pragma unroll
    for (int mf = 0; mf < 2; ++mf)
        #pragma unroll
        for (int nf = 0; nf < 2; ++nf)
            #pragma unroll
            for (int reg = 0; reg < 4; ++reg) {
                int b = m0 + wr * 32 + mf * 16 + l4 * 4 + reg;
                int h = n0 + wc * 32 + nf * 16 + l15;
                qs[(size_t)b * Hm + h] = acc[mf][nf][reg] + lqb[h] + lsb[h] + lkb[h];
            }
}

// ---------------------------------------------------------------------------
// k_scores_mfma (dominant): E = phib(102400x512) @ lkwb^T, bf16 MFMA.
// 2-phase double-buffered pipeline: STAGE(kt+1) issued before compute(kt),
// counted s_waitcnt vmcnt(4) (the 4 in-flight next-tile global_load_lds),
// raw s_barrier (no vmcnt drain), sched_barrier(0) fence after MFMA block.
// 128x128 tile, 4 waves 2x2, 4x4 frags, BK=32. Fused tanh/v_w/row-sum epilogue.
// ---------------------------------------------------------------------------
__global__ __launch_bounds__(256) void k_scores_mfma(
        const u16* __restrict__ phib, const u16* __restrict__ lkwb,
        const float* __restrict__ qs2, const float* __restrict__ vw,
        float* __restrict__ scores) {
    __shared__ u16 Asl[2][128 * 32];
    __shared__ u16 Bsl[2][128 * 32];
    const int n0 = blockIdx.x * 128;
    const int m0 = blockIdx.y * 128;
    const int t  = m0 >> 11;
    const int b0 = m0 & (Bm - 1);
    const int tid = threadIdx.x, lane = tid & 63, wid = tid >> 6;
    const int wr = wid >> 1, wc = wid & 1;
    const int l15 = lane & 15, l4 = lane >> 4;
    const int srow_base = (wid << 5) + (lane >> 2);   // + j*16
    const int schunk = lane & 3;

    f32x4 acc[4][4];
    #pragma unroll
    for (int i = 0; i < 4; ++i)
        #pragma unroll
        for (int j = 0; j < 4; ++j) acc[i][j] = (f32x4){0.f, 0.f, 0.f, 0.f};

    // stage one 128x32 K-tile of A and B into buffer `buf` (4 gload16/thread)
    auto STAGE = [&](int buf, int k0) {
        #pragma unroll
        for (int j = 0; j < 2; ++j) {
            int r = srow_base + j * 16;
            int gc = schunk ^ ((r >> 1) & 3);
            gload16(phib + (size_t)(m0 + r) * 512 + k0 + gc * 8,
                    &Asl[buf][((wid << 5) + j * 16) * 32]);
            gload16(lkwb + (size_t)(n0 + r) * 512 + k0 + gc * 8,
                    &Bsl[buf][((wid << 5) + j * 16) * 32]);
        }
    };
    auto COMPUTE = [&](int buf) {
        short8 af[4], bf[4];
        #pragma unroll
        for (int mf = 0; mf < 4; ++mf) {
            int r = wr * 64 + mf * 16 + l15;
            af[mf] = *(const short8*)&Asl[buf][r * 32 + (l4 ^ ((r >> 1) & 3)) * 8];
        }
        #pragma unroll
        for (int nf = 0; nf < 4; ++nf) {
            int r = wc * 64 + nf * 16 + l15;
            bf[nf] = *(const short8*)&Bsl[buf][r * 32 + (l4 ^ ((r >> 1) & 3)) * 8];
        }
        #pragma unroll
        for (int mf = 0; mf < 4; ++mf)
            #pragma unroll
            for (int nf = 0; nf < 4; ++nf)
                acc[mf][nf] = __builtin_amdgcn_mfma_f32_16x16x32_bf16(
                                  af[mf], bf[nf], acc[mf][nf], 0, 0, 0);
    };

    STAGE(0, 0);
    int cur = 0;
    #pragma unroll 1
    for (int kt = 0; kt < 15; ++kt) {
        STAGE(cur ^ 1, (kt + 1) << 5);                     // prefetch next tile
        asm volatile("s_waitcnt vmcnt(4)" ::: "memory");   // cur tile landed; 4 stay in flight
        __builtin_amdgcn_s_barrier();                      // all waves staged cur
        COMPUTE(cur);
        __builtin_amdgcn_sched_barrier(0);                 // pin reads/MFMA above barrier
        __builtin_amdgcn_s_barrier();                      // all reads of cur done
        cur ^= 1;
    }
    asm volatile("s_waitcnt vmcnt(0)" ::: "memory");
    __builtin_amdgcn_s_barrier();
    COMPUTE(cur);

    // epilogue: tanh + v_w dot + row-sum, one atomicAdd per row per wave
    float vws[4];
    int av[4];
    #pragma unroll
    for (int nf = 0; nf < 4; ++nf) {
        av[nf] = n0 + wc * 64 + nf * 16 + l15;
        vws[nf] = vw[av[nf]];
    }
    #pragma unroll
    for (int mf = 0; mf < 4; ++mf) {
        #pragma unroll
        for (int reg = 0; reg < 4; ++reg) {
            int b = b0 + wr * 64 + mf * 16 + l4 * 4 + reg;
            const float* q = qs2 + (size_t)b * Hm;
            float s = 0.f;
            #pragma unroll
            for (int nf = 0; nf < 4; ++nf)
                s = fmaf(tanhf(acc[mf][nf][reg] + q[av[nf]]), vws[nf], s);
            #pragma unroll
            for (int o = 1; o < 16; o <<= 1) s += __shfl_xor(s, o);
            if (l15 == 0) atomicAdd(&scores[(size_t)b * Tm + t], s);
        }
    }
}

// ---------------------------------------------------------------------------
// k_attn: softmax over T, weighted sums over bf16 phi + fp32 cell.
// ---------------------------------------------------------------------------
__global__ __launch_bounds__(256) void k_attn(
        const u16* __restrict__ phib, const float* __restrict__ cell,
        const float* __restrict__ scores,
        u16* __restrict__ Xb, float* __restrict__ cs) {
    __shared__ float p[Tm];
    const int b = blockIdx.x;
    const int tid = threadIdx.x;
    if (tid < 64) {
        float s = (tid < Tm) ? scores[(size_t)b * Tm + tid] : -INFINITY;
        float m = s;
        #pragma unroll
        for (int o = 32; o; o >>= 1) m = fmaxf(m, __shfl_xor(m, o));
        float ex = (tid < Tm) ? __expf(s - m) : 0.f;
        float sum = ex;
        #pragma unroll
        for (int o = 32; o; o >>= 1) sum += __shfl_xor(sum, o);
        if (tid < Tm) p[tid] = ex / sum;
    }
    __syncthreads();
    const int c0 = tid * 2;
    float ah0 = 0.f, ah1 = 0.f, ac0 = 0.f, ac1 = 0.f;
    for (int t = 0; t < Tm; ++t) {
        float w = p[t];
        const size_t rb = ((size_t)t * Bm + b) * 512 + c0;
        u32 ph2 = *(const u32*)&phib[rb];
        float2 ce2 = *(const float2*)&cell[rb];
        float p0 = __uint_as_float(ph2 << 16);
        float p1 = __uint_as_float(ph2 & 0xFFFF0000u);
        ah0 = fmaf(w, p0, ah0);
        ah1 = fmaf(w, p1, ah1);
        ac0 = fmaf(w, ce2.x, ac0);
        ac1 = fmaf(w, ce2.y, ac1);
    }
    *(u32*)&Xb[(size_t)b * KWp + c0] = (u32)bfr(ah0) | ((u32)bfr(ah1) << 16);
    *(float2*)&cs[(size_t)b * Hm + c0] = make_float2(ac0, ac1);
}

// ---------------------------------------------------------------------------
// k_gates_mfma: gates[2048][2048] = Xb(2048x832) @ Wg^T(2048x832), bf16 MFMA.
// ---------------------------------------------------------------------------
__global__ __launch_bounds__(256) void k_gates_mfma(
        const u16* __restrict__ Xb, const u16* __restrict__ Wg,
        float* __restrict__ gates) {
    __shared__ u16 Asl[64 * 32];
    __shared__ u16 Bsl[128 * 32];
    const int m0 = blockIdx.x * 64, n0 = blockIdx.y * 128;
    const int tid = threadIdx.x, lane = tid & 63, wid = tid >> 6;
    const int wr = wid >> 1, wc = wid & 1;
    const int l15 = lane & 15, l4 = lane >> 4;
    const int srow = (wid << 4) + (lane >> 2);
    const int gchunkA = (lane & 3) ^ ((srow >> 1) & 3);
    f32x4 acc[2][4];
    #pragma unroll
    for (int i = 0; i < 2; ++i)
        #pragma unroll
        for (int j = 0; j < 4; ++j) acc[i][j] = (f32x4){0.f, 0.f, 0.f, 0.f};

    for (int k0 = 0; k0 < KWp; k0 += 32) {
        __syncthreads();
        gload16(Xb + (size_t)(m0 + srow) * KWp + k0 + gchunkA * 8, &Asl[wid * 512]);
        #pragma unroll
        for (int j = 0; j < 2; ++j) {
            int brow = (wid << 5) + (j << 4) + (lane >> 2);
            int gchunkB = (lane & 3) ^ ((brow >> 1) & 3);
            gload16(Wg + (size_t)(n0 + brow) * KWp + k0 + gchunkB * 8,
                    &Bsl[wid * 1024 + j * 512]);
        }
        __syncthreads();
        short8 af[2], bf[4];
        #pragma unroll
        for (int mf = 0; mf < 2; ++mf) {
            int r = wr * 32 + mf * 16 + l15;
            af[mf] = *(const short8*)&Asl[r * 32 + (l4 ^ ((r >> 1) & 3)) * 8];
        }
        #pragma unroll
        for (int nf = 0; nf < 4; ++nf) {
            int r = wc * 64 + nf * 16 + l15;
            bf[nf] = *(const short8*)&Bsl[r * 32 + (l4 ^ ((r >> 1) & 3)) * 8];
        }
        #pragma unroll
        for (int mf = 0; mf < 2; ++mf)
            #pragma unroll
            for (int nf = 0; nf < 4; ++nf)
                acc[mf][nf] = __builtin_amdgcn_mfma_f32_16x16x32_bf16(
                                  af[mf], bf[nf], acc[mf][nf], 0, 0, 0);
    }
    #pragma unroll
    for (int mf = 0; mf < 2; ++mf)
        #pragma unroll
        for (int nf = 0; nf < 4; ++nf)
            #pragma unroll
            for (int reg = 0; reg < 4; ++reg) {
                int b = m0 + wr * 32 + mf * 16 + l4 * 4 + reg;
                int n = n0 + wc * 64 + nf * 16 + l15;
                gates[(size_t)b * 2048 + n] = acc[mf][nf][reg];
            }
}

// ---------------------------------------------------------------------------
// k_lstm: elementwise LSTM epilogue over [B,H].
// ---------------------------------------------------------------------------
__global__ __launch_bounds__(256) void k_lstm(
        const float* __restrict__ gates, const float* __restrict__ Wb,
        const float* __restrict__ cs, float* __restrict__ out) {
    const int idx = blockIdx.x * 256 + threadIdx.x;
    const int b = idx >> 9, h = idx & 511;
    const float* g = gates + (size_t)b * 2048;
    float f  = sigmoidf_(g[h]        + Wb[h]);
    float o  = sigmoidf_(g[512 + h]  + Wb[512 + h]);
    float ii = sigmoidf_(g[1024 + h] + Wb[1024 + h]);
    float ch = tanhf(    g[1536 + h] + Wb[1536 + h]);
    float c  = f * cs[idx] + ii * ch;
    out[idx] = o * tanhf(c);
}

extern "C" void kernel_launch(void* const* d_in, const int* in_sizes, int n_in,
                              void* d_out, int out_size, void* d_ws, size_t ws_size,
                              hipStream_t stream) {
    const float* x      = (const float*)d_in[0];
    const float* h_enc  = (const float*)d_in[1];
    const float* phi    = (const float*)d_in[2];
    const float* cell   = (const float*)d_in[3];
    const float* h_summ = (const float*)d_in[4];
    // d_in[5] c_summ: unused by the reference
    const float* W_w    = (const float*)d_in[6];
    const float* W_b    = (const float*)d_in[7];
    const float* v_w    = (const float*)d_in[8];
    // d_in[9] v_b: softmax-invariant, dropped
    const float* lq_w   = (const float*)d_in[10];
    const float* lq_b   = (const float*)d_in[11];
    const float* lk_w   = (const float*)d_in[12];
    const float* lk_b   = (const float*)d_in[13];
    const float* ls_w   = (const float*)d_in[14];
    const float* ls_b   = (const float*)d_in[15];
    float* out = (float*)d_out;

    char* w = (char*)d_ws;
    // phib: 0 .. 104,857,600 (52.4M bf16). gates (16.78 MB) ALIASES phib:
    // phib's last reader (k_attn) finishes before k_gates_mfma writes gates.
    u16*   phib   = (u16*)  (w);
    float* gates  = (float*)(w);
    float* qs     = (float*)(w + 104857600);                // 4.00 MB
    float* scores = (float*)(w + 109051904);                // 0.40 MB
    float* cs     = (float*)(w + 109461504);                // 4.00 MB
    u16*   Aq     = (u16*)  (w + 113655808);                // 4.19 MB
    u16*   Wq     = (u16*)  (w + 117850112);                // 1.05 MB
    u16*   Wg     = (u16*)  (w + 118898688);                // 3.41 MB
    u16*   Xb     = (u16*)  (w + 122306560);                // 3.41 MB
    u16*   lkwb   = (u16*)  (w + 125714432);                // 0.52 MB (end ~126.2 MB)

    hipMemsetAsync(scores, 0, (size_t)Bm * Tm * sizeof(float), stream);
    k_pack<<<dim3(2048, 5), 256, 0, stream>>>(h_enc, h_summ, lq_w, ls_w, W_w, x, lk_w,
                                              Aq, Wq, Wg, Xb, lkwb);
    k_pack_phi<<<dim3(2048), 256, 0, stream>>>(phi, phib);
    k_qs_mfma<<<dim3(Bm / 64, Hm / 64), 256, 0, stream>>>(Aq, Wq, lq_b, ls_b, lk_b, qs);
    k_scores_mfma<<<dim3(Hm / 128, (Tm * Bm) / 128), 256, 0, stream>>>(phib, lkwb, qs, v_w, scores);
    k_attn<<<dim3(Bm), 256, 0, stream>>>(phib, cell, scores, Xb, cs);
    k_gates_mfma<<<dim3(Bm / 64, 2048 / 128), 256, 0, stream>>>(Xb, Wg, gates);
    k_lstm<<<dim3((Bm * Hm) / 256), 256, 0, stream>>>(gates, W_b, cs, out);
}

// Round 6
// 344.458 us; speedup vs baseline: 1.0036x; 1.0036x over previous
//
#include <hip/hip_runtime.h>
#include <math.h>

#define Bm 2048
#define Hm 512
#define Em 300
#define Tm 50
#define KWm 812   // H + E
#define KWp 832   // padded to multiple of 32

typedef unsigned short u16;
typedef unsigned int u32;
typedef __attribute__((ext_vector_type(8))) short short8;
typedef __attribute__((ext_vector_type(8))) u16 ushort8v;
typedef __attribute__((ext_vector_type(4))) float f32x4;

__device__ __forceinline__ float sigmoidf_(float x) { return 1.f / (1.f + __expf(-x)); }

// fp32 -> bf16 bits, round-to-nearest-even
__device__ __forceinline__ u16 bfr(float x) {
    union { float f; u32 u; } c; c.f = x;
    u32 u = c.u;
    u += 0x7FFFu + ((u >> 16) & 1u);
    return (u16)(u >> 16);
}
__device__ __forceinline__ ushort8v cvt8(const float* __restrict__ p) {
    f32x4 v0 = *(const f32x4*)p;
    f32x4 v1 = *(const f32x4*)(p + 4);
    ushort8v r;
    r[0] = bfr(v0[0]); r[1] = bfr(v0[1]); r[2] = bfr(v0[2]); r[3] = bfr(v0[3]);
    r[4] = bfr(v1[0]); r[5] = bfr(v1[1]); r[6] = bfr(v1[2]); r[7] = bfr(v1[3]);
    return r;
}

// async global(bf16,16B) -> LDS, linear dest (wave-uniform base + lane*16)
__device__ __forceinline__ void gload16(const u16* g, u16* l) {
    __builtin_amdgcn_global_load_lds((const __attribute__((address_space(1))) void*)g,
                                     (__attribute__((address_space(3))) void*)l, 16, 0, 0);
}

// ---------------------------------------------------------------------------
// k_pack_phi: phi fp32 [T*B*512] -> bf16, grid-stride, 8 elems/thread/iter.
// ---------------------------------------------------------------------------
__global__ __launch_bounds__(256) void k_pack_phi(
        const float* __restrict__ phi, u16* __restrict__ phib) {
    const size_t nvec = (size_t)Tm * Bm * 512 / 8;
    for (size_t i = (size_t)blockIdx.x * 256 + threadIdx.x; i < nvec;
         i += (size_t)gridDim.x * 256)
        *(ushort8v*)&phib[i * 8] = cvt8(phi + i * 8);
}

// ---------------------------------------------------------------------------
// k_pack: small bf16 conversions/concats.
// job 0: Aq[2048][1024] = bf16([h_enc | h_summ])
// job 1: Wq[512][1024]  = bf16([lq_w | ls_w])
// job 2: Wg[2048][832]  = bf16(W_w) zero-padded
// job 3: Xb[2048][512..831] = bf16(x) zero-padded
// job 4: lkwb[512][512] = bf16(lk_w)
// ---------------------------------------------------------------------------
__global__ __launch_bounds__(256) void k_pack(
        const float* __restrict__ henc, const float* __restrict__ hsum,
        const float* __restrict__ lq, const float* __restrict__ ls,
        const float* __restrict__ Ww, const float* __restrict__ x,
        const float* __restrict__ lkw,
        u16* __restrict__ Aq, u16* __restrict__ Wq,
        u16* __restrict__ Wg, u16* __restrict__ Xb, u16* __restrict__ lkwb) {
    const int job = blockIdx.y;
    const int r = blockIdx.x;
    const int tid = threadIdx.x;
    if (job == 0) {
        for (int c = tid; c < 1024; c += 256) {
            float v = (c < 512) ? henc[(size_t)r * 512 + c] : hsum[(size_t)r * 512 + (c - 512)];
            Aq[(size_t)r * 1024 + c] = bfr(v);
        }
    } else if (job == 1) {
        if (r < 512)
            for (int c = tid; c < 1024; c += 256) {
                float v = (c < 512) ? lq[(size_t)r * 512 + c] : ls[(size_t)r * 512 + (c - 512)];
                Wq[(size_t)r * 1024 + c] = bfr(v);
            }
    } else if (job == 2) {
        for (int c = tid; c < KWp; c += 256)
            Wg[(size_t)r * KWp + c] = (c < KWm) ? bfr(Ww[(size_t)r * KWm + c]) : (u16)0;
    } else if (job == 3) {
        for (int c = 512 + tid; c < KWp; c += 256)
            Xb[(size_t)r * KWp + c] = (c < KWm) ? bfr(x[(size_t)r * Em + (c - 512)]) : (u16)0;
    } else {
        if (r < 512)
            for (int c = tid; c < 512; c += 256)
                lkwb[(size_t)r * 512 + c] = bfr(lkw[(size_t)r * 512 + c]);
    }
}

// ---------------------------------------------------------------------------
// k_qs_mfma: qs[b,h] = [h_enc|h_summ]·[lq|ls]^T + (lq_b+ls_b+lk_b)[h]
// ---------------------------------------------------------------------------
__global__ __launch_bounds__(256) void k_qs_mfma(
        const u16* __restrict__ Aq, const u16* __restrict__ Wq,
        const float* __restrict__ lqb, const float* __restrict__ lsb,
        const float* __restrict__ lkb, float* __restrict__ qs) {
    __shared__ u16 Asl[64 * 32];
    __shared__ u16 Bsl[64 * 32];
    const int m0 = blockIdx.x * 64, n0 = blockIdx.y * 64;
    const int tid = threadIdx.x, lane = tid & 63, wid = tid >> 6;
    const int wr = wid >> 1, wc = wid & 1;
    const int l15 = lane & 15, l4 = lane >> 4;
    const int srow = (wid << 4) + (lane >> 2);
    const int gchunk = (lane & 3) ^ ((srow >> 1) & 3);
    f32x4 acc[2][2];
    #pragma unroll
    for (int i = 0; i < 2; ++i)
        #pragma unroll
        for (int j = 0; j < 2; ++j) acc[i][j] = (f32x4){0.f, 0.f, 0.f, 0.f};

    for (int k0 = 0; k0 < 1024; k0 += 32) {
        __syncthreads();
        gload16(Aq + (size_t)(m0 + srow) * 1024 + k0 + gchunk * 8, &Asl[wid * 512]);
        gload16(Wq + (size_t)(n0 + srow) * 1024 + k0 + gchunk * 8, &Bsl[wid * 512]);
        __syncthreads();
        short8 af[2], bf[2];
        #pragma unroll
        for (int mf = 0; mf < 2; ++mf) {
            int r = wr * 32 + mf * 16 + l15;
            af[mf] = *(const short8*)&Asl[r * 32 + (l4 ^ ((r >> 1) & 3)) * 8];
        }
        #pragma unroll
        for (int nf = 0; nf < 2; ++nf) {
            int r = wc * 32 + nf * 16 + l15;
            bf[nf] = *(const short8*)&Bsl[r * 32 + (l4 ^ ((r >> 1) & 3)) * 8];
        }
        #pragma unroll
        for (int mf = 0; mf < 2; ++mf)
            #pragma unroll
            for (int nf = 0; nf < 2; ++nf)
                acc[mf][nf] = __builtin_amdgcn_mfma_f32_16x16x32_bf16(
                                  af[mf], bf[nf], acc[mf][nf], 0, 0, 0);
    }
    #pragma unroll
    for (int mf = 0; mf < 2; ++mf)
        #pragma unroll
        for (int nf = 0; nf < 2; ++nf)
            #pragma unroll
            for (int reg = 0; reg < 4; ++reg) {
                int b = m0 + wr * 32 + mf * 16 + l4 * 4 + reg;
                int h = n0 + wc * 32 + nf * 16 + l15;
                qs[(size_t)b * Hm + h] = acc[mf][nf][reg] + lqb[h] + lsb[h] + lkb[h];
            }
}

// ---------------------------------------------------------------------------
// k_scores_mfma (dominant): E = phib(102400x512) @ lkwb^T, bf16 MFMA.
// R6: (1) XCD-bijective block swizzle (3200 = 8 XCD x 400), n-tile fastest
//     within an XCD -> the 4 consumers of each A-panel run back-to-back on
//     ONE XCD -> A is an L2 hit for 3 of 4 (kills the 2x HBM re-fetch).
// (2) depth-3 prefetch: 3 LDS buffers, STAGE(kt+2) before COMPUTE(kt),
//     counted s_waitcnt vmcnt(8) (2 tiles x 4 loads in flight), raw
//     s_barrier, full unroll so waitcnt immediates and buffer indices fold.
// 128x128 tile, 4 waves 2x2, 4x4 frags, BK=32. Fused tanh/v_w/row-sum epilogue.
// ---------------------------------------------------------------------------
__global__ __launch_bounds__(256) void k_scores_mfma(
        const u16* __restrict__ phib, const u16* __restrict__ lkwb,
        const float* __restrict__ qs2, const float* __restrict__ vw,
        float* __restrict__ scores) {
    __shared__ u16 Asl[3][128 * 32];
    __shared__ u16 Bsl[3][128 * 32];
    // XCD swizzle: HW round-robins consecutive dispatch ids over 8 XCDs.
    const int d  = blockIdx.x;
    const int wg = (d & 7) * 400 + (d >> 3);
    const int n0 = (wg & 3) << 7;          // 4 n-tiles, fastest within XCD
    const int m0 = (wg >> 2) << 7;         // contiguous m-range per XCD
    const int t  = m0 >> 11;
    const int b0 = m0 & (Bm - 1);
    const int tid = threadIdx.x, lane = tid & 63, wid = tid >> 6;
    const int wr = wid >> 1, wc = wid & 1;
    const int l15 = lane & 15, l4 = lane >> 4;
    const int srow_base = (wid << 5) + (lane >> 2);   // + j*16
    const int schunk = lane & 3;

    f32x4 acc[4][4];
    #pragma unroll
    for (int i = 0; i < 4; ++i)
        #pragma unroll
        for (int j = 0; j < 4; ++j) acc[i][j] = (f32x4){0.f, 0.f, 0.f, 0.f};

    // stage one 128x32 K-tile of A and B into buffer `buf` (4 gload16/thread)
    auto STAGE = [&](int buf, int kt) {
        const int k0 = kt << 5;
        #pragma unroll
        for (int j = 0; j < 2; ++j) {
            int r = srow_base + j * 16;
            int gc = schunk ^ ((r >> 1) & 3);
            gload16(phib + (size_t)(m0 + r) * 512 + k0 + gc * 8,
                    &Asl[buf][((wid << 5) + j * 16) * 32]);
            gload16(lkwb + (size_t)(n0 + r) * 512 + k0 + gc * 8,
                    &Bsl[buf][((wid << 5) + j * 16) * 32]);
        }
    };
    auto COMPUTE = [&](int buf) {
        short8 af[4], bf[4];
        #pragma unroll
        for (int mf = 0; mf < 4; ++mf) {
            int r = wr * 64 + mf * 16 + l15;
            af[mf] = *(const short8*)&Asl[buf][r * 32 + (l4 ^ ((r >> 1) & 3)) * 8];
        }
        #pragma unroll
        for (int nf = 0; nf < 4; ++nf) {
            int r = wc * 64 + nf * 16 + l15;
            bf[nf] = *(const short8*)&Bsl[buf][r * 32 + (l4 ^ ((r >> 1) & 3)) * 8];
        }
        #pragma unroll
        for (int mf = 0; mf < 4; ++mf)
            #pragma unroll
            for (int nf = 0; nf < 4; ++nf)
                acc[mf][nf] = __builtin_amdgcn_mfma_f32_16x16x32_bf16(
                                  af[mf], bf[nf], acc[mf][nf], 0, 0, 0);
    };

    STAGE(0, 0);
    STAGE(1, 1);
    int rd = 0;
    #pragma unroll
    for (int kt = 0; kt < 16; ++kt) {
        if (kt < 14) {
            STAGE(rd == 0 ? 2 : rd - 1, kt + 2);           // prefetch 2 ahead
            asm volatile("s_waitcnt vmcnt(8)" ::: "memory"); // tile kt landed
        } else if (kt == 14) {
            asm volatile("s_waitcnt vmcnt(4)" ::: "memory");
        } else {
            asm volatile("s_waitcnt vmcnt(0)" ::: "memory");
        }
        __builtin_amdgcn_s_barrier();                      // all waves staged kt
        __builtin_amdgcn_sched_barrier(0);
        COMPUTE(rd);
        __builtin_amdgcn_sched_barrier(0);                 // pin reads above bar2
        __builtin_amdgcn_s_barrier();                      // reads of buf done
        rd = (rd == 2) ? 0 : rd + 1;
    }

    // epilogue: tanh + v_w dot + row-sum, one atomicAdd per row per wave
    float vws[4];
    int av[4];
    #pragma unroll
    for (int nf = 0; nf < 4; ++nf) {
        av[nf] = n0 + wc * 64 + nf * 16 + l15;
        vws[nf] = vw[av[nf]];
    }
    #pragma unroll
    for (int mf = 0; mf < 4; ++mf) {
        #pragma unroll
        for (int reg = 0; reg < 4; ++reg) {
            int b = b0 + wr * 64 + mf * 16 + l4 * 4 + reg;
            const float* q = qs2 + (size_t)b * Hm;
            float s = 0.f;
            #pragma unroll
            for (int nf = 0; nf < 4; ++nf)
                s = fmaf(tanhf(acc[mf][nf][reg] + q[av[nf]]), vws[nf], s);
            #pragma unroll
            for (int o = 1; o < 16; o <<= 1) s += __shfl_xor(s, o);
            if (l15 == 0) atomicAdd(&scores[(size_t)b * Tm + t], s);
        }
    }
}

// ---------------------------------------------------------------------------
// k_attn: softmax over T, weighted sums over bf16 phi + fp32 cell.
// ---------------------------------------------------------------------------
__global__ __launch_bounds__(256) void k_attn(
        const u16* __restrict__ phib, const float* __restrict__ cell,
        const float* __restrict__ scores,
        u16* __restrict__ Xb, float* __restrict__ cs) {
    __shared__ float p[Tm];
    const int b = blockIdx.x;
    const int tid = threadIdx.x;
    if (tid < 64) {
        float s = (tid < Tm) ? scores[(size_t)b * Tm + tid] : -INFINITY;
        float m = s;
        #pragma unroll
        for (int o = 32; o; o >>= 1) m = fmaxf(m, __shfl_xor(m, o));
        float ex = (tid < Tm) ? __expf(s - m) : 0.f;
        float sum = ex;
        #pragma unroll
        for (int o = 32; o; o >>= 1) sum += __shfl_xor(sum, o);
        if (tid < Tm) p[tid] = ex / sum;
    }
    __syncthreads();
    const int c0 = tid * 2;
    float ah0 = 0.f, ah1 = 0.f, ac0 = 0.f, ac1 = 0.f;
    for (int t = 0; t < Tm; ++t) {
        float w = p[t];
        const size_t rb = ((size_t)t * Bm + b) * 512 + c0;
        u32 ph2 = *(const u32*)&phib[rb];
        float2 ce2 = *(const float2*)&cell[rb];
        float p0 = __uint_as_float(ph2 << 16);
        float p1 = __uint_as_float(ph2 & 0xFFFF0000u);
        ah0 = fmaf(w, p0, ah0);
        ah1 = fmaf(w, p1, ah1);
        ac0 = fmaf(w, ce2.x, ac0);
        ac1 = fmaf(w, ce2.y, ac1);
    }
    *(u32*)&Xb[(size_t)b * KWp + c0] = (u32)bfr(ah0) | ((u32)bfr(ah1) << 16);
    *(float2*)&cs[(size_t)b * Hm + c0] = make_float2(ac0, ac1);
}

// ---------------------------------------------------------------------------
// k_gates_mfma: gates[2048][2048] = Xb(2048x832) @ Wg^T(2048x832), bf16 MFMA.
// ---------------------------------------------------------------------------
__global__ __launch_bounds__(256) void k_gates_mfma(
        const u16* __restrict__ Xb, const u16* __restrict__ Wg,
        float* __restrict__ gates) {
    __shared__ u16 Asl[64 * 32];
    __shared__ u16 Bsl[128 * 32];
    const int m0 = blockIdx.x * 64, n0 = blockIdx.y * 128;
    const int tid = threadIdx.x, lane = tid & 63, wid = tid >> 6;
    const int wr = wid >> 1, wc = wid & 1;
    const int l15 = lane & 15, l4 = lane >> 4;
    const int srow = (wid << 4) + (lane >> 2);
    const int gchunkA = (lane & 3) ^ ((srow >> 1) & 3);
    f32x4 acc[2][4];
    #pragma unroll
    for (int i = 0; i < 2; ++i)
        #pragma unroll
        for (int j = 0; j < 4; ++j) acc[i][j] = (f32x4){0.f, 0.f, 0.f, 0.f};

    for (int k0 = 0; k0 < KWp; k0 += 32) {
        __syncthreads();
        gload16(Xb + (size_t)(m0 + srow) * KWp + k0 + gchunkA * 8, &Asl[wid * 512]);
        #pragma unroll
        for (int j = 0; j < 2; ++j) {
            int brow = (wid << 5) + (j << 4) + (lane >> 2);
            int gchunkB = (lane & 3) ^ ((brow >> 1) & 3);
            gload16(Wg + (size_t)(n0 + brow) * KWp + k0 + gchunkB * 8,
                    &Bsl[wid * 1024 + j * 512]);
        }
        __syncthreads();
        short8 af[2], bf[4];
        #pragma unroll
        for (int mf = 0; mf < 2; ++mf) {
            int r = wr * 32 + mf * 16 + l15;
            af[mf] = *(const short8*)&Asl[r * 32 + (l4 ^ ((r >> 1) & 3)) * 8];
        }
        #pragma unroll
        for (int nf = 0; nf < 4; ++nf) {
            int r = wc * 64 + nf * 16 + l15;
            bf[nf] = *(const short8*)&Bsl[r * 32 + (l4 ^ ((r >> 1) & 3)) * 8];
        }
        #pragma unroll
        for (int mf = 0; mf < 2; ++mf)
            #pragma unroll
            for (int nf = 0; nf < 4; ++nf)
                acc[mf][nf] = __builtin_amdgcn_mfma_f32_16x16x32_bf16(
                                  af[mf], bf[nf], acc[mf][nf], 0, 0, 0);
    }
    #pragma unroll
    for (int mf = 0; mf < 2; ++mf)
        #pragma unroll
        for (int nf = 0; nf < 4; ++nf)
            #pragma unroll
            for (int reg = 0; reg < 4; ++reg) {
                int b = m0 + wr * 32 + mf * 16 + l4 * 4 + reg;
                int n = n0 + wc * 64 + nf * 16 + l15;
                gates[(size_t)b * 2048 + n] = acc[mf][nf][reg];
            }
}

// ---------------------------------------------------------------------------
// k_lstm: elementwise LSTM epilogue over [B,H].
// ---------------------------------------------------------------------------
__global__ __launch_bounds__(256) void k_lstm(
        const float* __restrict__ gates, const float* __restrict__ Wb,
        const float* __restrict__ cs, float* __restrict__ out) {
    const int idx = blockIdx.x * 256 + threadIdx.x;
    const int b = idx >> 9, h = idx & 511;
    const float* g = gates + (size_t)b * 2048;
    float f  = sigmoidf_(g[h]        + Wb[h]);
    float o  = sigmoidf_(g[512 + h]  + Wb[512 + h]);
    float ii = sigmoidf_(g[1024 + h] + Wb[1024 + h]);
    float ch = tanhf(    g[1536 + h] + Wb[1536 + h]);
    float c  = f * cs[idx] + ii * ch;
    out[idx] = o * tanhf(c);
}

extern "C" void kernel_launch(void* const* d_in, const int* in_sizes, int n_in,
                              void* d_out, int out_size, void* d_ws, size_t ws_size,
                              hipStream_t stream) {
    const float* x      = (const float*)d_in[0];
    const float* h_enc  = (const float*)d_in[1];
    const float* phi    = (const float*)d_in[2];
    const float* cell   = (const float*)d_in[3];
    const float* h_summ = (const float*)d_in[4];
    // d_in[5] c_summ: unused by the reference
    const float* W_w    = (const float*)d_in[6];
    const float* W_b    = (const float*)d_in[7];
    const float* v_w    = (const float*)d_in[8];
    // d_in[9] v_b: softmax-invariant, dropped
    const float* lq_w   = (const float*)d_in[10];
    const float* lq_b   = (const float*)d_in[11];
    const float* lk_w   = (const float*)d_in[12];
    const float* lk_b   = (const float*)d_in[13];
    const float* ls_w   = (const float*)d_in[14];
    const float* ls_b   = (const float*)d_in[15];
    float* out = (float*)d_out;

    char* w = (char*)d_ws;
    // phib: 0 .. 104,857,600 (52.4M bf16). gates (16.78 MB) ALIASES phib:
    // phib's last reader (k_attn) finishes before k_gates_mfma writes gates.
    u16*   phib   = (u16*)  (w);
    float* gates  = (float*)(w);
    float* qs     = (float*)(w + 104857600);                // 4.00 MB
    float* scores = (float*)(w + 109051904);                // 0.40 MB
    float* cs     = (float*)(w + 109461504);                // 4.00 MB
    u16*   Aq     = (u16*)  (w + 113655808);                // 4.19 MB
    u16*   Wq     = (u16*)  (w + 117850112);                // 1.05 MB
    u16*   Wg     = (u16*)  (w + 118898688);                // 3.41 MB
    u16*   Xb     = (u16*)  (w + 122306560);                // 3.41 MB
    u16*   lkwb   = (u16*)  (w + 125714432);                // 0.52 MB (end ~126.2 MB)

    hipMemsetAsync(scores, 0, (size_t)Bm * Tm * sizeof(float), stream);
    k_pack<<<dim3(2048, 5), 256, 0, stream>>>(h_enc, h_summ, lq_w, ls_w, W_w, x, lk_w,
                                              Aq, Wq, Wg, Xb, lkwb);
    k_pack_phi<<<dim3(2048), 256, 0, stream>>>(phi, phib);
    k_qs_mfma<<<dim3(Bm / 64, Hm / 64), 256, 0, stream>>>(Aq, Wq, lq_b, ls_b, lk_b, qs);
    k_scores_mfma<<<dim3(3200), 256, 0, stream>>>(phib, lkwb, qs, v_w, scores);
    k_attn<<<dim3(Bm), 256, 0, stream>>>(phib, cell, scores, Xb, cs);
    k_gates_mfma<<<dim3(Bm / 64, 2048 / 128), 256, 0, stream>>>(Xb, Wg, gates);
    k_lstm<<<dim3((Bm * Hm) / 256), 256, 0, stream>>>(gates, W_b, cs, out);
}

// Round 7
// 310.537 us; speedup vs baseline: 1.1132x; 1.1092x over previous
//
#include <hip/hip_runtime.h>
#include <math.h>

#define Bm 2048
#define Hm 512
#define Em 300
#define Tm 50
#define KWm 812   // H + E
#define KWp 832   // padded to multiple of 32

typedef unsigned short u16;
typedef unsigned int u32;
typedef __attribute__((ext_vector_type(8))) short short8;
typedef __attribute__((ext_vector_type(8))) u16 ushort8v;
typedef __attribute__((ext_vector_type(4))) float f32x4;

__device__ __forceinline__ float sigmoidf_(float x) { return 1.f / (1.f + __expf(-x)); }
// fast tanh: exact at saturation, ~6 VALU ops (vs ~25-40 for libm tanhf; no -ffast-math in harness)
__device__ __forceinline__ float tanhfast(float x) { return 1.f - 2.f / (__expf(2.f * x) + 1.f); }

// fp32 -> bf16 bits, round-to-nearest-even
__device__ __forceinline__ u16 bfr(float x) {
    union { float f; u32 u; } c; c.f = x;
    u32 u = c.u;
    u += 0x7FFFu + ((u >> 16) & 1u);
    return (u16)(u >> 16);
}
__device__ __forceinline__ ushort8v cvt8(const float* __restrict__ p) {
    f32x4 v0 = *(const f32x4*)p;
    f32x4 v1 = *(const f32x4*)(p + 4);
    ushort8v r;
    r[0] = bfr(v0[0]); r[1] = bfr(v0[1]); r[2] = bfr(v0[2]); r[3] = bfr(v0[3]);
    r[4] = bfr(v1[0]); r[5] = bfr(v1[1]); r[6] = bfr(v1[2]); r[7] = bfr(v1[3]);
    return r;
}

// async global(bf16,16B) -> LDS, linear dest (wave-uniform base + lane*16)
__device__ __forceinline__ void gload16(const u16* g, u16* l) {
    __builtin_amdgcn_global_load_lds((const __attribute__((address_space(1))) void*)g,
                                     (__attribute__((address_space(3))) void*)l, 16, 0, 0);
}

// ---------------------------------------------------------------------------
// k_pack_phi: phi fp32 [T*B*512] -> bf16, grid-stride, 8 elems/thread/iter.
// ---------------------------------------------------------------------------
__global__ __launch_bounds__(256) void k_pack_phi(
        const float* __restrict__ phi, u16* __restrict__ phib) {
    const size_t nvec = (size_t)Tm * Bm * 512 / 8;
    for (size_t i = (size_t)blockIdx.x * 256 + threadIdx.x; i < nvec;
         i += (size_t)gridDim.x * 256)
        *(ushort8v*)&phib[i * 8] = cvt8(phi + i * 8);
}

// ---------------------------------------------------------------------------
// k_pack: small bf16 conversions/concats.
// job 0: Aq[2048][1024] = bf16([h_enc | h_summ])
// job 1: Wq[512][1024]  = bf16([lq_w | ls_w])
// job 2: Wg[2048][832]  = bf16(W_w) zero-padded
// job 3: Xb[2048][512..831] = bf16(x) zero-padded
// job 4: lkwb[512][512] = bf16(lk_w)
// ---------------------------------------------------------------------------
__global__ __launch_bounds__(256) void k_pack(
        const float* __restrict__ henc, const float* __restrict__ hsum,
        const float* __restrict__ lq, const float* __restrict__ ls,
        const float* __restrict__ Ww, const float* __restrict__ x,
        const float* __restrict__ lkw,
        u16* __restrict__ Aq, u16* __restrict__ Wq,
        u16* __restrict__ Wg, u16* __restrict__ Xb, u16* __restrict__ lkwb) {
    const int job = blockIdx.y;
    const int r = blockIdx.x;
    const int tid = threadIdx.x;
    if (job == 0) {
        for (int c = tid; c < 1024; c += 256) {
            float v = (c < 512) ? henc[(size_t)r * 512 + c] : hsum[(size_t)r * 512 + (c - 512)];
            Aq[(size_t)r * 1024 + c] = bfr(v);
        }
    } else if (job == 1) {
        if (r < 512)
            for (int c = tid; c < 1024; c += 256) {
                float v = (c < 512) ? lq[(size_t)r * 512 + c] : ls[(size_t)r * 512 + (c - 512)];
                Wq[(size_t)r * 1024 + c] = bfr(v);
            }
    } else if (job == 2) {
        for (int c = tid; c < KWp; c += 256)
            Wg[(size_t)r * KWp + c] = (c < KWm) ? bfr(Ww[(size_t)r * KWm + c]) : (u16)0;
    } else if (job == 3) {
        for (int c = 512 + tid; c < KWp; c += 256)
            Xb[(size_t)r * KWp + c] = (c < KWm) ? bfr(x[(size_t)r * Em + (c - 512)]) : (u16)0;
    } else {
        if (r < 512)
            for (int c = tid; c < 512; c += 256)
                lkwb[(size_t)r * 512 + c] = bfr(lkw[(size_t)r * 512 + c]);
    }
}

// ---------------------------------------------------------------------------
// k_qs_mfma: qs[b,h] = [h_enc|h_summ]·[lq|ls]^T + (lq_b+ls_b+lk_b)[h]
// ---------------------------------------------------------------------------
__global__ __launch_bounds__(256) void k_qs_mfma(
        const u16* __restrict__ Aq, const u16* __restrict__ Wq,
        const float* __restrict__ lqb, const float* __restrict__ lsb,
        const float* __restrict__ lkb, float* __restrict__ qs) {
    __shared__ u16 Asl[64 * 32];
    __shared__ u16 Bsl[64 * 32];
    const int m0 = blockIdx.x * 64, n0 = blockIdx.y * 64;
    const int tid = threadIdx.x, lane = tid & 63, wid = tid >> 6;
    const int wr = wid >> 1, wc = wid & 1;
    const int l15 = lane & 15, l4 = lane >> 4;
    const int srow = (wid << 4) + (lane >> 2);
    const int gchunk = (lane & 3) ^ ((srow >> 1) & 3);
    f32x4 acc[2][2];
    #pragma unroll
    for (int i = 0; i < 2; ++i)
        #pragma unroll
        for (int j = 0; j < 2; ++j) acc[i][j] = (f32x4){0.f, 0.f, 0.f, 0.f};

    for (int k0 = 0; k0 < 1024; k0 += 32) {
        __syncthreads();
        gload16(Aq + (size_t)(m0 + srow) * 1024 + k0 + gchunk * 8, &Asl[wid * 512]);
        gload16(Wq + (size_t)(n0 + srow) * 1024 + k0 + gchunk * 8, &Bsl[wid * 512]);
        __syncthreads();
        short8 af[2], bf[2];
        #pragma unroll
        for (int mf = 0; mf < 2; ++mf) {
            int r = wr * 32 + mf * 16 + l15;
            af[mf] = *(const short8*)&Asl[r * 32 + (l4 ^ ((r >> 1) & 3)) * 8];
        }
        #pragma unroll
        for (int nf = 0; nf < 2; ++nf) {
            int r = wc * 32 + nf * 16 + l15;
            bf[nf] = *(const short8*)&Bsl[r * 32 + (l4 ^ ((r >> 1) & 3)) * 8];
        }
        #pragma unroll
        for (int mf = 0; mf < 2; ++mf)
            #pragma unroll
            for (int nf = 0; nf < 2; ++nf)
                acc[mf][nf] = __builtin_amdgcn_mfma_f32_16x16x32_bf16(
                                  af[mf], bf[nf], acc[mf][nf], 0, 0, 0);
    }
    #pragma unroll
    for (int mf = 0; mf < 2; ++mf)
        #pragma unroll
        for (int nf = 0; nf < 2; ++nf)
            #pragma unroll
            for (int reg = 0; reg < 4; ++reg) {
                int b = m0 + wr * 32 + mf * 16 + l4 * 4 + reg;
                int h = n0 + wc * 32 + nf * 16 + l15;
                qs[(size_t)b * Hm + h] = acc[mf][nf][reg] + lqb[h] + lsb[h] + lkb[h];
            }
}

// ---------------------------------------------------------------------------
// k_scores_mfma (dominant): E = phib(102400x512) @ lkwb^T, bf16 MFMA.
// R7: BK=64 -> 8 K-iters (half the barrier intervals, 32 MFMA/wave/iter),
// single-buffered 32KB LDS, simple drain (__syncthreads) structure which
// empirically tied the pipelined variants. 8-chunk XOR swizzle (both-sides
// involution): global source chunk (lane&7)^(row&7), linear LDS dest,
// ds_read slot c^(row&7) -> 2-way (free) on reads. XCD-bijective block
// swizzle kept (FETCH 215->128MB verified). setprio(1) around MFMA cluster.
// Fused fast-tanh/v_w/row-sum epilogue, atomicAdd into scores.
// ---------------------------------------------------------------------------
__global__ __launch_bounds__(256) void k_scores_mfma(
        const u16* __restrict__ phib, const u16* __restrict__ lkwb,
        const float* __restrict__ qs2, const float* __restrict__ vw,
        float* __restrict__ scores) {
    __shared__ u16 Asl[128 * 64];
    __shared__ u16 Bsl[128 * 64];
    // XCD swizzle: HW round-robins consecutive dispatch ids over 8 XCDs.
    const int d  = blockIdx.x;
    const int wg = (d & 7) * 400 + (d >> 3);
    const int n0 = (wg & 3) << 7;          // 4 n-tiles, fastest within XCD
    const int m0 = (wg >> 2) << 7;         // contiguous m-range per XCD
    const int t  = m0 >> 11;
    const int b0 = m0 & (Bm - 1);
    const int tid = threadIdx.x, lane = tid & 63, wid = tid >> 6;
    const int wr = wid >> 1, wc = wid & 1;
    const int l15 = lane & 15, l4 = lane >> 4;
    // staging: instruction j covers rows wid*32 + j*8 + (lane>>3); chunk slot lane&7
    const int srow_in = lane >> 3;                 // 0..7 within 8-row group
    const int schunk  = (lane & 7) ^ srow_in;      // inverse-swizzled source chunk

    f32x4 acc[4][4];
    #pragma unroll
    for (int i = 0; i < 4; ++i)
        #pragma unroll
        for (int j = 0; j < 4; ++j) acc[i][j] = (f32x4){0.f, 0.f, 0.f, 0.f};

    for (int kt = 0; kt < 8; ++kt) {
        const int k0 = kt << 6;
        __syncthreads();   // previous iter's reads complete
        #pragma unroll
        for (int j = 0; j < 4; ++j) {
            int r = (wid << 5) + (j << 3) + srow_in;        // 0..127
            gload16(phib + (size_t)(m0 + r) * 512 + k0 + schunk * 8,
                    &Asl[((wid << 5) + (j << 3)) * 64]);
            gload16(lkwb + (size_t)(n0 + r) * 512 + k0 + schunk * 8,
                    &Bsl[((wid << 5) + (j << 3)) * 64]);
        }
        __syncthreads();   // drains vmcnt -> tile visible to all waves
        short8 af[4][2], bf[4][2];
        #pragma unroll
        for (int mf = 0; mf < 4; ++mf) {
            int r = wr * 64 + mf * 16 + l15;
            #pragma unroll
            for (int ks = 0; ks < 2; ++ks) {
                int c = ks * 4 + l4;
                af[mf][ks] = *(const short8*)&Asl[r * 64 + (c ^ (r & 7)) * 8];
            }
        }
        #pragma unroll
        for (int nf = 0; nf < 4; ++nf) {
            int r = wc * 64 + nf * 16 + l15;
            #pragma unroll
            for (int ks = 0; ks < 2; ++ks) {
                int c = ks * 4 + l4;
                bf[nf][ks] = *(const short8*)&Bsl[r * 64 + (c ^ (r & 7)) * 8];
            }
        }
        __builtin_amdgcn_s_setprio(1);
        #pragma unroll
        for (int ks = 0; ks < 2; ++ks)
            #pragma unroll
            for (int mf = 0; mf < 4; ++mf)
                #pragma unroll
                for (int nf = 0; nf < 4; ++nf)
                    acc[mf][nf] = __builtin_amdgcn_mfma_f32_16x16x32_bf16(
                                      af[mf][ks], bf[nf][ks], acc[mf][nf], 0, 0, 0);
        __builtin_amdgcn_s_setprio(0);
    }

    // epilogue: fast tanh + v_w dot + row-sum, one atomicAdd per row per wave
    float vws[4];
    int av[4];
    #pragma unroll
    for (int nf = 0; nf < 4; ++nf) {
        av[nf] = n0 + wc * 64 + nf * 16 + l15;
        vws[nf] = vw[av[nf]];
    }
    #pragma unroll
    for (int mf = 0; mf < 4; ++mf) {
        #pragma unroll
        for (int reg = 0; reg < 4; ++reg) {
            int b = b0 + wr * 64 + mf * 16 + l4 * 4 + reg;
            const float* q = qs2 + (size_t)b * Hm;
            float s = 0.f;
            #pragma unroll
            for (int nf = 0; nf < 4; ++nf)
                s = fmaf(tanhfast(acc[mf][nf][reg] + q[av[nf]]), vws[nf], s);
            #pragma unroll
            for (int o = 1; o < 16; o <<= 1) s += __shfl_xor(s, o);
            if (l15 == 0) atomicAdd(&scores[(size_t)b * Tm + t], s);
        }
    }
}

// ---------------------------------------------------------------------------
// k_attn: softmax over T, weighted sums over bf16 phi + fp32 cell.
// ---------------------------------------------------------------------------
__global__ __launch_bounds__(256) void k_attn(
        const u16* __restrict__ phib, const float* __restrict__ cell,
        const float* __restrict__ scores,
        u16* __restrict__ Xb, float* __restrict__ cs) {
    __shared__ float p[Tm];
    const int b = blockIdx.x;
    const int tid = threadIdx.x;
    if (tid < 64) {
        float s = (tid < Tm) ? scores[(size_t)b * Tm + tid] : -INFINITY;
        float m = s;
        #pragma unroll
        for (int o = 32; o; o >>= 1) m = fmaxf(m, __shfl_xor(m, o));
        float ex = (tid < Tm) ? __expf(s - m) : 0.f;
        float sum = ex;
        #pragma unroll
        for (int o = 32; o; o >>= 1) sum += __shfl_xor(sum, o);
        if (tid < Tm) p[tid] = ex / sum;
    }
    __syncthreads();
    const int c0 = tid * 2;
    float ah0 = 0.f, ah1 = 0.f, ac0 = 0.f, ac1 = 0.f;
    for (int t = 0; t < Tm; ++t) {
        float w = p[t];
        const size_t rb = ((size_t)t * Bm + b) * 512 + c0;
        u32 ph2 = *(const u32*)&phib[rb];
        float2 ce2 = *(const float2*)&cell[rb];
        float p0 = __uint_as_float(ph2 << 16);
        float p1 = __uint_as_float(ph2 & 0xFFFF0000u);
        ah0 = fmaf(w, p0, ah0);
        ah1 = fmaf(w, p1, ah1);
        ac0 = fmaf(w, ce2.x, ac0);
        ac1 = fmaf(w, ce2.y, ac1);
    }
    *(u32*)&Xb[(size_t)b * KWp + c0] = (u32)bfr(ah0) | ((u32)bfr(ah1) << 16);
    *(float2*)&cs[(size_t)b * Hm + c0] = make_float2(ac0, ac1);
}

// ---------------------------------------------------------------------------
// k_gates_mfma: gates[2048][2048] = Xb(2048x832) @ Wg^T(2048x832), bf16 MFMA.
// ---------------------------------------------------------------------------
__global__ __launch_bounds__(256) void k_gates_mfma(
        const u16* __restrict__ Xb, const u16* __restrict__ Wg,
        float* __restrict__ gates) {
    __shared__ u16 Asl[64 * 32];
    __shared__ u16 Bsl[128 * 32];
    const int m0 = blockIdx.x * 64, n0 = blockIdx.y * 128;
    const int tid = threadIdx.x, lane = tid & 63, wid = tid >> 6;
    const int wr = wid >> 1, wc = wid & 1;
    const int l15 = lane & 15, l4 = lane >> 4;
    const int srow = (wid << 4) + (lane >> 2);
    const int gchunkA = (lane & 3) ^ ((srow >> 1) & 3);
    f32x4 acc[2][4];
    #pragma unroll
    for (int i = 0; i < 2; ++i)
        #pragma unroll
        for (int j = 0; j < 4; ++j) acc[i][j] = (f32x4){0.f, 0.f, 0.f, 0.f};

    for (int k0 = 0; k0 < KWp; k0 += 32) {
        __syncthreads();
        gload16(Xb + (size_t)(m0 + srow) * KWp + k0 + gchunkA * 8, &Asl[wid * 512]);
        #pragma unroll
        for (int j = 0; j < 2; ++j) {
            int brow = (wid << 5) + (j << 4) + (lane >> 2);
            int gchunkB = (lane & 3) ^ ((brow >> 1) & 3);
            gload16(Wg + (size_t)(n0 + brow) * KWp + k0 + gchunkB * 8,
                    &Bsl[wid * 1024 + j * 512]);
        }
        __syncthreads();
        short8 af[2], bf[4];
        #pragma unroll
        for (int mf = 0; mf < 2; ++mf) {
            int r = wr * 32 + mf * 16 + l15;
            af[mf] = *(const short8*)&Asl[r * 32 + (l4 ^ ((r >> 1) & 3)) * 8];
        }
        #pragma unroll
        for (int nf = 0; nf < 4; ++nf) {
            int r = wc * 64 + nf * 16 + l15;
            bf[nf] = *(const short8*)&Bsl[r * 32 + (l4 ^ ((r >> 1) & 3)) * 8];
        }
        #pragma unroll
        for (int mf = 0; mf < 2; ++mf)
            #pragma unroll
            for (int nf = 0; nf < 4; ++nf)
                acc[mf][nf] = __builtin_amdgcn_mfma_f32_16x16x32_bf16(
                                  af[mf], bf[nf], acc[mf][nf], 0, 0, 0);
    }
    #pragma unroll
    for (int mf = 0; mf < 2; ++mf)
        #pragma unroll
        for (int nf = 0; nf < 4; ++nf)
            #pragma unroll
            for (int reg = 0; reg < 4; ++reg) {
                int b = m0 + wr * 32 + mf * 16 + l4 * 4 + reg;
                int n = n0 + wc * 64 + nf * 16 + l15;
                gates[(size_t)b * 2048 + n] = acc[mf][nf][reg];
            }
}

// ---------------------------------------------------------------------------
// k_lstm: elementwise LSTM epilogue over [B,H].
// ---------------------------------------------------------------------------
__global__ __launch_bounds__(256) void k_lstm(
        const float* __restrict__ gates, const float* __restrict__ Wb,
        const float* __restrict__ cs, float* __restrict__ out) {
    const int idx = blockIdx.x * 256 + threadIdx.x;
    const int b = idx >> 9, h = idx & 511;
    const float* g = gates + (size_t)b * 2048;
    float f  = sigmoidf_(g[h]        + Wb[h]);
    float o  = sigmoidf_(g[512 + h]  + Wb[512 + h]);
    float ii = sigmoidf_(g[1024 + h] + Wb[1024 + h]);
    float ch = tanhfast( g[1536 + h] + Wb[1536 + h]);
    float c  = f * cs[idx] + ii * ch;
    out[idx] = o * tanhfast(c);
}

extern "C" void kernel_launch(void* const* d_in, const int* in_sizes, int n_in,
                              void* d_out, int out_size, void* d_ws, size_t ws_size,
                              hipStream_t stream) {
    const float* x      = (const float*)d_in[0];
    const float* h_enc  = (const float*)d_in[1];
    const float* phi    = (const float*)d_in[2];
    const float* cell   = (const float*)d_in[3];
    const float* h_summ = (const float*)d_in[4];
    // d_in[5] c_summ: unused by the reference
    const float* W_w    = (const float*)d_in[6];
    const float* W_b    = (const float*)d_in[7];
    const float* v_w    = (const float*)d_in[8];
    // d_in[9] v_b: softmax-invariant, dropped
    const float* lq_w   = (const float*)d_in[10];
    const float* lq_b   = (const float*)d_in[11];
    const float* lk_w   = (const float*)d_in[12];
    const float* lk_b   = (const float*)d_in[13];
    const float* ls_w   = (const float*)d_in[14];
    const float* ls_b   = (const float*)d_in[15];
    float* out = (float*)d_out;

    char* w = (char*)d_ws;
    // phib: 0 .. 104,857,600 (52.4M bf16). gates (16.78 MB) ALIASES phib:
    // phib's last reader (k_attn) finishes before k_gates_mfma writes gates.
    u16*   phib   = (u16*)  (w);
    float* gates  = (float*)(w);
    float* qs     = (float*)(w + 104857600);                // 4.00 MB
    float* scores = (float*)(w + 109051904);                // 0.40 MB
    float* cs     = (float*)(w + 109461504);                // 4.00 MB
    u16*   Aq     = (u16*)  (w + 113655808);                // 4.19 MB
    u16*   Wq     = (u16*)  (w + 117850112);                // 1.05 MB
    u16*   Wg     = (u16*)  (w + 118898688);                // 3.41 MB
    u16*   Xb     = (u16*)  (w + 122306560);                // 3.41 MB
    u16*   lkwb   = (u16*)  (w + 125714432);                // 0.52 MB (end ~126.2 MB)

    hipMemsetAsync(scores, 0, (size_t)Bm * Tm * sizeof(float), stream);
    k_pack<<<dim3(2048, 5), 256, 0, stream>>>(h_enc, h_summ, lq_w, ls_w, W_w, x, lk_w,
                                              Aq, Wq, Wg, Xb, lkwb);
    k_pack_phi<<<dim3(2048), 256, 0, stream>>>(phi, phib);
    k_qs_mfma<<<dim3(Bm / 64, Hm / 64), 256, 0, stream>>>(Aq, Wq, lq_b, ls_b, lk_b, qs);
    k_scores_mfma<<<dim3(3200), 256, 0, stream>>>(phib, lkwb, qs, v_w, scores);
    k_attn<<<dim3(Bm), 256, 0, stream>>>(phib, cell, scores, Xb, cs);
    k_gates_mfma<<<dim3(Bm / 64, 2048 / 128), 256, 0, stream>>>(Xb, Wg, gates);
    k_lstm<<<dim3((Bm * Hm) / 256), 256, 0, stream>>>(gates, W_b, cs, out);
}